// Round 5
// baseline (628.504 us; speedup 1.0000x reference)
//
#include <hip/hip_runtime.h>
#include <hip/hip_bf16.h>
#include <stdint.h>

typedef __attribute__((ext_vector_type(8))) short short8;
typedef __attribute__((ext_vector_type(4))) float floatx4;

#define AS1 __attribute__((address_space(1)))
#define AS3 __attribute__((address_space(3)))

// async global->LDS, 16B/lane. HW dest = wave-uniform base + lane*16, so every
// call site ensures its lane's dst == base + lane*16 (contiguous by lane).
__device__ __forceinline__ void async_copy16(const void* g, void* l) {
    __builtin_amdgcn_global_load_lds((const AS1 uint32_t*)(uintptr_t)g,
                                     (AS3 uint32_t*)(uintptr_t)l, 16, 0, 0);
}

// load 8 f32 -> 8 bf16 packed
__device__ __forceinline__ short8 cvt8(const float* p) {
    float4 a = *(const float4*)p;
    float4 b = *(const float4*)(p + 4);
    union { short s[8]; short8 v; } u;
    __hip_bfloat16* h = (__hip_bfloat16*)u.s;
    h[0] = __float2bfloat16(a.x); h[1] = __float2bfloat16(a.y);
    h[2] = __float2bfloat16(a.z); h[3] = __float2bfloat16(a.w);
    h[4] = __float2bfloat16(b.x); h[5] = __float2bfloat16(b.y);
    h[6] = __float2bfloat16(b.z); h[7] = __float2bfloat16(b.w);
    return u.v;
}

// ---------------------------------------------------------------- cvt f32->bf16
__global__ __launch_bounds__(256) void cvt_bf16(const float* __restrict__ s,
                                                __hip_bfloat16* __restrict__ d, int n) {
    int i = ((int)blockIdx.x * 256 + (int)threadIdx.x) * 4;
    if (i >= n) return;
    const float4 v = *(const float4*)(s + i);
    ushort4 pk;
    __hip_bfloat16* ph = (__hip_bfloat16*)&pk;
    ph[0] = __float2bfloat16(v.x); ph[1] = __float2bfloat16(v.y);
    ph[2] = __float2bfloat16(v.z); ph[3] = __float2bfloat16(v.w);
    *(ushort4*)(d + i) = pk;
}

// ---------------------------------------------------------------- GEMM 256x256 8-phase
// C = A @ Bt^T + bias, M=8192 N=2048 K=2048, bf16 inputs, 512 thr = 8 waves 2Mx4N.
// BK=64 split in two k-halves; LDS arenas A/B x dbuf x khalf = [256 rows][64B],
// rows paired in 128B macro-rows, 16B chunk swizzle cc' = cc ^ (m&7) (verified:
// each 8-lane b128 read group covers 8 distinct bank groups -> conflict-free;
// global_load_lds dest stays linear, source carries the inverse swizzle).
// Schedule per K-tile: 4 phases (kh,mh); phase stages ONE half-stage of tile
// kt+1 in order (A,k0),(B,k0),(A,k1),(B,k1); vmcnt(4) only at phases 1,3:
//   enter iter: {A1,B1 of cur tile} in flight (4)
//   p0 +A0' (6) | p1 +B0' (8) -> vmcnt(4): cur-tile k1 landed (read at p2)
//   p2 +A1' (6) | p3 +B1' (8) -> vmcnt(4): next-tile k0 landed (read at p0')
// Never drains to 0 in steady state (T3+T4); setprio around MFMA cluster (T5).
template <int STORE_MODE>
__global__ __launch_bounds__(512, 2) void gemm256(const __hip_bfloat16* __restrict__ Ab,
                                                  const __hip_bfloat16* __restrict__ Bb,
                                                  const float* __restrict__ bias,
                                                  void* __restrict__ Cv) {
    constexpr int N = 2048, K = 2048;
    __shared__ __align__(16) char smem[131072];
    char* smemA = smem;            // [dbuf*2+kh]*16384
    char* smemB = smem + 65536;
    const int tid  = threadIdx.x;
    const int wave = tid >> 6, lane = tid & 63;
    const int quad = lane >> 4, l16 = lane & 15;
    const int wm = wave >> 2, wn = wave & 3;  // wave -> (M-half, N-quarter)
    // XCD-contiguous swizzle: 256 blocks round-robin 8 XCDs; give each XCD a
    // contiguous 4Mx8N panel set.
    const int wg = ((int)blockIdx.x & 7) * 32 + ((int)blockIdx.x >> 3);
    const int m0 = (wg >> 3) * 256;
    const int n0 = (wg & 7) * 256;

    // fragment read offset within a [256][64B] khalf arena (macro-row form)
    const int laneOff = (l16 >> 1) * 128 + (((((l16 & 1) << 2) | quad)) ^ (l16 >> 1)) * 16;

    // stage one (matrix, khalf) = 256 rows x 32 cols: 2 loads/thread
    auto stage2 = [&](const __hip_bfloat16* G, char* arena, int row0, int col0) {
#pragma unroll
        for (int i = 0; i < 2; ++i) {
            int s  = i * 512 + wave * 64 + lane;      // phys 16B slot
            int mm = i * 64 + wave * 8 + (lane >> 3); // macro-row; mm&7 == lane>>3
            int cc = (lane & 7) ^ (lane >> 3);        // logical chunk in macro-row
            int r  = 2 * mm + (cc >> 2);
            int c  = cc & 3;
            async_copy16(G + (size_t)(row0 + r) * K + col0 + c * 8, arena + s * 16);
        }
    };

    floatx4 acc[8][4];
#pragma unroll
    for (int i = 0; i < 8; ++i)
#pragma unroll
        for (int j = 0; j < 4; ++j) acc[i][j] = (floatx4)0.0f;

    const int nt = K / 64;  // 32 K-tiles

    // prologue: all four half-stages of tile 0 into buf0, wait the k0 pair only
    stage2(Ab, smemA + 0,     m0, 0);
    stage2(Bb, smemB + 0,     n0, 0);
    stage2(Ab, smemA + 16384, m0, 32);
    stage2(Bb, smemB + 16384, n0, 32);
    asm volatile("s_waitcnt vmcnt(4)" ::: "memory");
    __builtin_amdgcn_s_barrier();
    __builtin_amdgcn_sched_barrier(0);

    for (int kt = 0; kt < nt; ++kt) {
        const int  cur  = kt & 1;
        const bool st   = (kt + 1) < nt;
        const int  colb = (kt + 1) * 64;
#pragma unroll
        for (int kh = 0; kh < 2; ++kh) {
            const char* Ab_ = smemA + ((cur << 1) + kh) * 16384 + wm * 8192;
            const char* Bb_ = smemB + ((cur << 1) + kh) * 16384 + wn * 4096;
            short8 bf[4];
#pragma unroll
            for (int mh = 0; mh < 2; ++mh) {
                if (st) {  // stage order: (A,k0) (B,k0) (A,k1) (B,k1)
                    if (mh == 0)
                        stage2(Ab, smemA + (((cur ^ 1) << 1) + kh) * 16384, m0, colb + kh * 32);
                    else
                        stage2(Bb, smemB + (((cur ^ 1) << 1) + kh) * 16384, n0, colb + kh * 32);
                }
                short8 af[4];
#pragma unroll
                for (int i = 0; i < 4; ++i)
                    af[i] = *(const short8*)(Ab_ + (mh * 4 + i) * 1024 + laneOff);
                if (mh == 0) {
#pragma unroll
                    for (int n = 0; n < 4; ++n)
                        bf[n] = *(const short8*)(Bb_ + n * 1024 + laneOff);
                }
                __builtin_amdgcn_s_barrier();      // align waves; reads issued above
                __builtin_amdgcn_sched_barrier(0);
                __builtin_amdgcn_s_setprio(1);
#pragma unroll
                for (int i = 0; i < 4; ++i)
#pragma unroll
                    for (int n = 0; n < 4; ++n)
                        acc[mh * 4 + i][n] = __builtin_amdgcn_mfma_f32_16x16x32_bf16(
                            af[i], bf[n], acc[mh * 4 + i][n], 0, 0, 0);
                __builtin_amdgcn_s_setprio(0);
                if (mh == 1) {  // counted wait, once per k-half pair (phases 1,3)
                    if (st) asm volatile("s_waitcnt vmcnt(4)" ::: "memory");
                    else    asm volatile("s_waitcnt vmcnt(0)" ::: "memory");
                }
                __builtin_amdgcn_s_barrier();
                __builtin_amdgcn_sched_barrier(0);
            }
        }
    }

    // epilogue: per wave 128x64 block of C
#pragma unroll
    for (int mf = 0; mf < 8; ++mf) {
#pragma unroll
        for (int nf = 0; nf < 4; ++nf) {
            int col  = n0 + wn * 64 + nf * 16 + l16;
            float bv = bias[col];
#pragma unroll
            for (int r = 0; r < 4; ++r) {
                int row = m0 + wm * 128 + mf * 16 + quad * 4 + r;
                float v = acc[mf][nf][r] + bv;
                if (STORE_MODE == 0) {
                    ((float*)Cv)[(size_t)row * N + col] = v;
                } else if (STORE_MODE == 1) {
                    ((__hip_bfloat16*)Cv)[(size_t)row * N + col] = __float2bfloat16(v);
                } else {
                    int s = row >> 2, b = row & 3, nh = col >> 7, d = col & 127;
                    ((__hip_bfloat16*)Cv)[((size_t)(b * 16 + nh) * 128 + d) * 2048 + s] =
                        __float2bfloat16(v);
                }
            }
        }
    }
}

// ---------------------------------------------------------------- GEMM (legacy 128x128)
// kept for the tight-workspace path (f32 inputs, sync cvt).
template <int A_ASYNC, int B_ASYNC, int STORE_MODE>
__global__ __launch_bounds__(256, 2) void gemm_k(const void* __restrict__ Av,
                                                 const void* __restrict__ Bv,
                                                 const float* __restrict__ bias,
                                                 void* __restrict__ Cv,
                                                 int M, int N, int K) {
    __shared__ __align__(16) __hip_bfloat16 sA[128 * 32];
    __shared__ __align__(16) __hip_bfloat16 sB[128 * 32];
    const int tid  = threadIdx.x;
    const int wave = tid >> 6, lane = tid & 63;
    const int quad = lane >> 4, l16 = lane & 15;
    const int m0 = blockIdx.x * 128, n0 = blockIdx.y * 128;
    const int wm = (wave >> 1) * 64, wn = (wave & 1) * 64;
    const int lrow   = lane >> 2;
    const int srcoff = (((lane & 3) ^ ((lane >> 3) & 3)) * 16);
    const int dstoff = (lane & 3) * 16;
    const int swzq   = (quad ^ ((l16 >> 1) & 3)) * 16;

    floatx4 acc[4][4];
#pragma unroll
    for (int i = 0; i < 4; i++)
#pragma unroll
        for (int j = 0; j < 4; j++) acc[i][j] = (floatx4)0.0f;

    for (int k0 = 0; k0 < K; k0 += 32) {
        short8 va[2], vb[2];
#pragma unroll
        for (int c = 0; c < 2; ++c) {
            int r = wave * 32 + c * 16 + lrow;
            if (!A_ASYNC) va[c] = cvt8((const float*)Av + (size_t)(m0 + r) * K + k0 + (lane & 3) * 8);
            if (!B_ASYNC) vb[c] = cvt8((const float*)Bv + (size_t)(n0 + r) * K + k0 + (lane & 3) * 8);
        }
        __syncthreads();
#pragma unroll
        for (int c = 0; c < 2; ++c) {
            int r = wave * 32 + c * 16 + lrow;
            if (A_ASYNC)
                async_copy16((const char*)((const __hip_bfloat16*)Av + (size_t)(m0 + r) * K + k0) + srcoff,
                             (char*)sA + r * 64 + dstoff);
            else
                *(short8*)((char*)sA + r * 64 + srcoff) = va[c];
            if (B_ASYNC)
                async_copy16((const char*)((const __hip_bfloat16*)Bv + (size_t)(n0 + r) * K + k0) + srcoff,
                             (char*)sB + r * 64 + dstoff);
            else
                *(short8*)((char*)sB + r * 64 + srcoff) = vb[c];
        }
        __syncthreads();

        short8 af[4], bf[4];
#pragma unroll
        for (int i = 0; i < 4; i++)
            af[i] = *(const short8*)((const char*)sA + (wm + i * 16 + l16) * 64 + swzq);
#pragma unroll
        for (int j = 0; j < 4; j++)
            bf[j] = *(const short8*)((const char*)sB + (wn + j * 16 + l16) * 64 + swzq);
#pragma unroll
        for (int i = 0; i < 4; i++)
#pragma unroll
            for (int j = 0; j < 4; j++)
                acc[i][j] = __builtin_amdgcn_mfma_f32_16x16x32_bf16(af[i], bf[j], acc[i][j], 0, 0, 0);
    }

#pragma unroll
    for (int i = 0; i < 4; i++) {
#pragma unroll
        for (int j = 0; j < 4; j++) {
            int col  = n0 + wn + j * 16 + l16;
            float bv = bias[col];
#pragma unroll
            for (int r = 0; r < 4; ++r) {
                int row = m0 + wm + i * 16 + quad * 4 + r;
                float v = acc[i][j][r] + bv;
                if (STORE_MODE == 0) {
                    ((float*)Cv)[(size_t)row * N + col] = v;
                } else if (STORE_MODE == 1) {
                    ((__hip_bfloat16*)Cv)[(size_t)row * N + col] = __float2bfloat16(v);
                } else {
                    int s = row >> 2, b = row & 3, nh = col >> 7, d = col & 127;
                    ((__hip_bfloat16*)Cv)[((size_t)(b * 16 + nh) * 128 + d) * 2048 + s] =
                        __float2bfloat16(v);
                }
            }
        }
    }
}

// ---------------------------------------------------------------- RoPE (in-place)
__global__ __launch_bounds__(256) void rope_kernel(__hip_bfloat16* __restrict__ Q,
                                                   __hip_bfloat16* __restrict__ K) {
    const int PER = 8192 * 16 * 32;
    int idx = (int)blockIdx.x * 256 + (int)threadIdx.x;
    __hip_bfloat16* base = (idx < PER) ? Q : K;
    int i  = (idx < PER) ? idx : idx - PER;
    int p  = i & 31;
    int nh = (i >> 5) & 15;
    int t  = i >> 9;
    int s  = t >> 2;
    float inv = __expf(-(float)(p & 15) * 0.5756462732485115f);  // ln(10000)/16
    float ang = (float)s * inv;
    float c = cosf(ang), sn = sinf(ang);
    size_t off = (size_t)t * 2048 + nh * 128 + 2 * p;
    float x0 = __bfloat162float(base[off]);
    float x1 = __bfloat162float(base[off + 1]);
    base[off]     = __float2bfloat16(x0 * c - x1 * sn);
    base[off + 1] = __float2bfloat16(x0 * sn + x1 * c);
}

// ---------------------------------------------------------------- flash attention
// (unchanged from round 4: swapped-operand in-register softmax + T3/T4 counted
//  vmcnt double-buffer; verified 123us, MfmaUtil 25%)
__global__ __launch_bounds__(256, 2) void attn_kernel(__hip_bfloat16* __restrict__ Qio,
                                                      const __hip_bfloat16* __restrict__ Km,
                                                      const __hip_bfloat16* __restrict__ Vt) {
    __shared__ __align__(16) char smem[65536];
    const int tid  = threadIdx.x;
    const int wave = tid >> 6, lane = tid & 63;
    const int quad = lane >> 4, l16 = lane & 15;
    const int bh = blockIdx.x, b = bh >> 4, nh = bh & 15;
    const int qtl = 15 - (int)blockIdx.y;
    const int q0  = qtl * 128;
    const int lrow    = lane >> 2;
    const int dstoff  = (lane & 3) * 16;
    const int srcoffV = (((lane & 3) ^ ((lane >> 3) & 3)) * 16);
    const int swzqV   = (quad ^ ((l16 >> 1) & 3)) * 16;
    const float scale = 0.08838834764831845f;

    auto stage = [&](int kt, int p) {
        char* sKb = smem + p * 32768;
        char* sVb = sKb + 16384;
#pragma unroll
        for (int c = 0; c < 4; ++c) {
            int krow = c * 16 + lrow;
            int swzK = ((krow >> 1) & 1) | (((krow >> 3) & 1) << 1);
            int srcK = ((lane & 3) ^ swzK) * 16;
            int t    = (kt * 64 + krow) * 4 + b;
            async_copy16((const char*)(Km + (size_t)t * 2048 + nh * 128 + wave * 32) + srcK,
                         sKb + wave * 4096 + krow * 64 + dstoff);
        }
        const int kc = wave >> 1, dh = (wave & 1) * 64;
#pragma unroll
        for (int c = 0; c < 4; ++c) {
            int d = dh + c * 16 + lrow;
            async_copy16((const char*)(Vt + ((size_t)bh * 128 + d) * 2048 + kt * 64 + kc * 32) + srcoffV,
                         sVb + kc * 8192 + d * 64 + dstoff);
        }
    };

    short8 qf[2][4];
#pragma unroll
    for (int mg = 0; mg < 2; ++mg)
#pragma unroll
        for (int kk = 0; kk < 4; ++kk) {
            int qrow = wave * 32 + mg * 16 + l16;
            int t    = (q0 + qrow) * 4 + b;
            qf[mg][kk] = *(const short8*)(Qio + (size_t)t * 2048 + nh * 128 + kk * 32 + quad * 8);
        }

    float m_i[2], l_i[2];
#pragma unroll
    for (int mg = 0; mg < 2; ++mg) { m_i[mg] = -1e30f; l_i[mg] = 0.f; }
    floatx4 o_acc[2][8];
#pragma unroll
    for (int mg = 0; mg < 2; ++mg)
#pragma unroll
        for (int n = 0; n < 8; ++n) o_acc[mg][n] = (floatx4)0.0f;

    const int nk = 2 * qtl + 2;

    stage(0, 0);
    __syncthreads();

    for (int kt = 0; kt < nk; ++kt) {
        const int cur = kt & 1;
        if (kt + 1 < nk) {
            stage(kt + 1, cur ^ 1);
            asm volatile("s_waitcnt vmcnt(8)" ::: "memory");
        } else {
            asm volatile("s_waitcnt vmcnt(0)" ::: "memory");
        }
        __builtin_amdgcn_s_barrier();
        __builtin_amdgcn_sched_barrier(0);

        const char* sKb = smem + cur * 32768;
        const char* sVb = sKb + 16384;

        floatx4 sacc[2][4];
#pragma unroll
        for (int mg = 0; mg < 2; ++mg)
#pragma unroll
            for (int n = 0; n < 4; ++n) sacc[mg][n] = (floatx4)0.0f;
#pragma unroll
        for (int nt = 0; nt < 4; ++nt) {
            int R    = (nt >> 1) * 32 + (l16 >> 2) * 8 + (nt & 1) * 4 + (l16 & 3);
            int swzK = ((R >> 1) & 1) | (((R >> 3) & 1) << 1);
            int off  = R * 64 + (quad ^ swzK) * 16;
#pragma unroll
            for (int kk = 0; kk < 4; ++kk) {
                short8 ak = *(const short8*)(sKb + kk * 4096 + off);
                sacc[0][nt] = __builtin_amdgcn_mfma_f32_16x16x32_bf16(ak, qf[0][kk], sacc[0][nt], 0, 0, 0);
                sacc[1][nt] = __builtin_amdgcn_mfma_f32_16x16x32_bf16(ak, qf[1][kk], sacc[1][nt], 0, 0, 0);
            }
        }

        short8 ap[2][2];
#pragma unroll
        for (int mg = 0; mg < 2; ++mg) {
            const int q     = q0 + wave * 32 + mg * 16 + l16;
            const bool dmask = (kt * 64 + 63) > (q0 + wave * 32 + mg * 16);
            float mx = -1e30f;
#pragma unroll
            for (int nt = 0; nt < 4; ++nt) {
                int kvb = kt * 64 + (nt >> 1) * 32 + quad * 8 + (nt & 1) * 4;
#pragma unroll
                for (int r = 0; r < 4; ++r) {
                    float v = sacc[mg][nt][r] * scale;
                    if (dmask && (kvb + r > q)) v = -1e30f;
                    sacc[mg][nt][r] = v;
                    mx = fmaxf(mx, v);
                }
            }
            mx = fmaxf(mx, __shfl_xor(mx, 16, 64));
            mx = fmaxf(mx, __shfl_xor(mx, 32, 64));
            float mnew  = fmaxf(m_i[mg], mx);
            float alpha = __expf(m_i[mg] - mnew);
            m_i[mg] = mnew;
            float rs = 0.f;
#pragma unroll
            for (int nt = 0; nt < 4; ++nt)
#pragma unroll
                for (int r = 0; r < 4; ++r) {
                    float e = __expf(sacc[mg][nt][r] - mnew);
                    sacc[mg][nt][r] = e;
                    rs += e;
                }
            rs += __shfl_xor(rs, 16, 64);
            rs += __shfl_xor(rs, 32, 64);
            l_i[mg] = l_i[mg] * alpha + rs;
#pragma unroll
            for (int kc = 0; kc < 2; ++kc) {
                union { short s[8]; short8 v; } u;
                __hip_bfloat16* h = (__hip_bfloat16*)u.s;
                h[0] = __float2bfloat16(sacc[mg][2 * kc][0]);
                h[1] = __float2bfloat16(sacc[mg][2 * kc][1]);
                h[2] = __float2bfloat16(sacc[mg][2 * kc][2]);
                h[3] = __float2bfloat16(sacc[mg][2 * kc][3]);
                h[4] = __float2bfloat16(sacc[mg][2 * kc + 1][0]);
                h[5] = __float2bfloat16(sacc[mg][2 * kc + 1][1]);
                h[6] = __float2bfloat16(sacc[mg][2 * kc + 1][2]);
                h[7] = __float2bfloat16(sacc[mg][2 * kc + 1][3]);
                ap[mg][kc] = u.v;
            }
#pragma unroll
            for (int nt = 0; nt < 8; ++nt)
#pragma unroll
                for (int r = 0; r < 4; ++r) o_acc[mg][nt][r] *= alpha;
        }

#pragma unroll
        for (int kc = 0; kc < 2; ++kc)
#pragma unroll
            for (int nt = 0; nt < 8; ++nt) {
                short8 av = *(const short8*)(sVb + kc * 8192 + (nt * 16 + l16) * 64 + swzqV);
                o_acc[0][nt] = __builtin_amdgcn_mfma_f32_16x16x32_bf16(av, ap[0][kc], o_acc[0][nt], 0, 0, 0);
                o_acc[1][nt] = __builtin_amdgcn_mfma_f32_16x16x32_bf16(av, ap[1][kc], o_acc[1][nt], 0, 0, 0);
            }

        asm volatile("s_waitcnt lgkmcnt(0)" ::: "memory");
        __builtin_amdgcn_s_barrier();
        __builtin_amdgcn_sched_barrier(0);
    }

    char* sO = smem + wave * 4096;
#pragma unroll
    for (int mg = 0; mg < 2; ++mg) {
        float inv = 1.0f / l_i[mg];
#pragma unroll
        for (int nt = 0; nt < 8; ++nt) {
            union { short h[4]; uint2 v; } u;
            __hip_bfloat16* hh = (__hip_bfloat16*)u.h;
            hh[0] = __float2bfloat16(o_acc[mg][nt][0] * inv);
            hh[1] = __float2bfloat16(o_acc[mg][nt][1] * inv);
            hh[2] = __float2bfloat16(o_acc[mg][nt][2] * inv);
            hh[3] = __float2bfloat16(o_acc[mg][nt][3] * inv);
            int pc = (2 * nt + (quad >> 1)) ^ ((l16 >> 1) & 3);
            *(uint2*)(sO + l16 * 256 + pc * 16 + (quad & 1) * 8) = u.v;
        }
#pragma unroll
        for (int cc = 0; cc < 4; ++cc) {
            int qr  = lane >> 2;
            int c16 = (lane & 3) + cc * 4;
            int pc  = c16 ^ ((qr >> 1) & 3);
            short8 ov = *(const short8*)(sO + qr * 256 + pc * 16);
            int s = q0 + wave * 32 + mg * 16 + qr;
            *(short8*)(Qio + (size_t)(s * 4 + b) * 2048 + nh * 128 + c16 * 8) = ov;
        }
    }
}

// ---------------------------------------------------------------- launch
extern "C" void kernel_launch(void* const* d_in, const int* in_sizes, int n_in,
                              void* d_out, int out_size, void* d_ws, size_t ws_size,
                              hipStream_t stream) {
    const float* x  = (const float*)d_in[0];
    const float* wq = (const float*)d_in[1];
    const float* bq = (const float*)d_in[2];
    const float* wk = (const float*)d_in[3];
    const float* bk = (const float*)d_in[4];
    const float* wv = (const float*)d_in[5];
    const float* bv = (const float*)d_in[6];
    const float* wd = (const float*)d_in[7];
    const float* bd = (const float*)d_in[8];
    // d_in[9] = start_pos: unused (reference recomputes t=arange(seq))

    const size_t TH = (size_t)8192 * 2048;  // 16.7M elems
    const size_t HH = (size_t)2048 * 2048;  // 4M elems

    if (ws_size >= (136ull << 20)) {
        // spacious: pre-convert to bf16; 256x256 8-phase GEMMs
        __hip_bfloat16* xb  = (__hip_bfloat16*)d_ws;
        __hip_bfloat16* Qb  = xb + TH;
        __hip_bfloat16* Kb  = Qb + TH;
        __hip_bfloat16* Vtb = Kb + TH;
        __hip_bfloat16* wb  = Vtb + TH;  // reused per GEMM

        cvt_bf16<<<(int)(TH / 1024), 256, 0, stream>>>(x, xb, (int)TH);
        cvt_bf16<<<(int)(HH / 1024), 256, 0, stream>>>(wq, wb, (int)HH);
        gemm256<1><<<256, 512, 0, stream>>>(xb, wb, bq, Qb);
        cvt_bf16<<<(int)(HH / 1024), 256, 0, stream>>>(wk, wb, (int)HH);
        gemm256<1><<<256, 512, 0, stream>>>(xb, wb, bk, Kb);
        cvt_bf16<<<(int)(HH / 1024), 256, 0, stream>>>(wv, wb, (int)HH);
        gemm256<2><<<256, 512, 0, stream>>>(xb, wb, bv, Vtb);

        rope_kernel<<<32768, 256, 0, stream>>>(Qb, Kb);
        attn_kernel<<<dim3(64, 16), 256, 0, stream>>>(Qb, Kb, Vtb);

        cvt_bf16<<<(int)(HH / 1024), 256, 0, stream>>>(wd, wb, (int)HH);
        gemm256<0><<<256, 512, 0, stream>>>(Qb, wb, bd, d_out);
    } else {
        // tight (96 MiB total scratch): Q in ws; K,Vt inside d_out (legacy path)
        __hip_bfloat16* Qb = (__hip_bfloat16*)d_ws;
        __hip_bfloat16* Kb = (__hip_bfloat16*)d_out;
        __hip_bfloat16* Vt = (__hip_bfloat16*)d_out + TH;
        dim3 gg(64, 16);

        gemm_k<0, 0, 1><<<gg, 256, 0, stream>>>(x, wq, bq, Qb, 8192, 2048, 2048);
        gemm_k<0, 0, 1><<<gg, 256, 0, stream>>>(x, wk, bk, Kb, 8192, 2048, 2048);
        gemm_k<0, 0, 2><<<gg, 256, 0, stream>>>(x, wv, bv, Vt, 8192, 2048, 2048);

        rope_kernel<<<32768, 256, 0, stream>>>(Qb, Kb);
        attn_kernel<<<dim3(64, 16), 256, 0, stream>>>(Qb, Kb, Vt);

        gemm_k<1, 0, 0><<<gg, 256, 0, stream>>>(Qb, wd, bd, d_out, 8192, 2048, 2048);
    }
    (void)in_sizes; (void)n_in; (void)out_size; (void)ws_size;
}

// Round 7
// 626.820 us; speedup vs baseline: 1.0027x; 1.0027x over previous
//
#include <hip/hip_runtime.h>
#include <hip/hip_bf16.h>
#include <stdint.h>

typedef __attribute__((ext_vector_type(8))) short short8;
typedef __attribute__((ext_vector_type(4))) float floatx4;

#define AS1 __attribute__((address_space(1)))
#define AS3 __attribute__((address_space(3)))

// async global->LDS, 16B/lane. HW dest = wave-uniform base + lane*16, so every
// call site ensures its lane's dst == base + lane*16 (contiguous by lane).
__device__ __forceinline__ void async_copy16(const void* g, void* l) {
    __builtin_amdgcn_global_load_lds((const AS1 uint32_t*)(uintptr_t)g,
                                     (AS3 uint32_t*)(uintptr_t)l, 16, 0, 0);
}

// load 8 f32 -> 8 bf16 packed
__device__ __forceinline__ short8 cvt8(const float* p) {
    float4 a = *(const float4*)p;
    float4 b = *(const float4*)(p + 4);
    union { short s[8]; short8 v; } u;
    __hip_bfloat16* h = (__hip_bfloat16*)u.s;
    h[0] = __float2bfloat16(a.x); h[1] = __float2bfloat16(a.y);
    h[2] = __float2bfloat16(a.z); h[3] = __float2bfloat16(a.w);
    h[4] = __float2bfloat16(b.x); h[5] = __float2bfloat16(b.y);
    h[6] = __float2bfloat16(b.z); h[7] = __float2bfloat16(b.w);
    return u.v;
}

// ---------------------------------------------------------------- cvt f32->bf16
__global__ __launch_bounds__(256) void cvt_bf16(const float* __restrict__ s,
                                                __hip_bfloat16* __restrict__ d, int n) {
    int i = ((int)blockIdx.x * 256 + (int)threadIdx.x) * 4;
    if (i >= n) return;
    const float4 v = *(const float4*)(s + i);
    ushort4 pk;
    __hip_bfloat16* ph = (__hip_bfloat16*)&pk;
    ph[0] = __float2bfloat16(v.x); ph[1] = __float2bfloat16(v.y);
    ph[2] = __float2bfloat16(v.z); ph[3] = __float2bfloat16(v.w);
    *(ushort4*)(d + i) = pk;
}

// ---------------------------------------------------------------- V transpose
// Vn [t][2048] -> Vt[(b*16+nh)*128+d][s]. s-fast thread mapping: writes are
// fully coalesced 16B/lane contiguous; reads are 2B gathers (stride 8KB) that
// the L2 absorbs via line reuse across d-neighboring blocks (r5 lesson: the
// SCATTERED side must be the read side, never the write side).
__global__ __launch_bounds__(256) void vtrans(const __hip_bfloat16* __restrict__ Vn,
                                              __hip_bfloat16* __restrict__ Vt) {
    int idx = (int)blockIdx.x * 256 + (int)threadIdx.x;
    int sc  = idx & 255;          // s-chunk (8 s each)
    int d   = (idx >> 8) & 127;
    int bh  = idx >> 15;          // b*16+nh
    int b   = bh >> 4, nh = bh & 15;
    union { short h[8]; short8 v; } u;
#pragma unroll
    for (int j = 0; j < 8; ++j) {
        int t = (sc * 8 + j) * 4 + b;
        u.h[j] = *(const short*)(Vn + (size_t)t * 2048 + nh * 128 + d);
    }
    *(short8*)(Vt + ((size_t)bh * 128 + d) * 2048 + sc * 8) = u.v;
}

// ---------------------------------------------------------------- GEMM 256x256
// C = A @ Bt^T + bias, M=8192 N=2048 K=2048, bf16 in, 512 thr = 8 waves 2Mx4N.
// BK=64 in two k-halves; arenas [256 rows][64B] per (matrix, dbuf, khalf),
// 128B macro-rows with 16B chunk swizzle cc' = cc ^ (mm&7) (conflict-free,
// verified r5: SQ_LDS_BANK_CONFLICT = 0).
// r6 schedule (fixes r5's lockstep alternation + short-distance vmcnt):
//   per K-tile: s_barrier; sched_barrier; issue ALL 4 half-stages of tile kt+1
//   (8 loads); vmcnt(8)  <- waits tile kt's 8 loads, issued one FULL tile
//   (~4 phases) earlier; sched_barrier; then both k-halves {12 ds_read_b128,
//   32 MFMA} with NO intra-tile barriers -> compiler interleaves kh=1 reads
//   under kh=0 MFMAs (real ds_read||MFMA overlap at last).
// Race ledger: stages target buf[cur^1]; its last readers ran in tile kt-1 and
// all passed this tile's top barrier (each ds_read feeds an MFMA, forcing the
// lgkmcnt wait before barrier). Reads of buf[cur] follow the vmcnt that retires
// its 8 loads. Barriers/waits uniform across waves -> no hang path.
template <int STORE_MODE>
__global__ __launch_bounds__(512, 2) void gemm256(const __hip_bfloat16* __restrict__ Ab,
                                                  const __hip_bfloat16* __restrict__ Bb,
                                                  const float* __restrict__ bias,
                                                  void* __restrict__ Cv) {
    constexpr int N = 2048, K = 2048;
    __shared__ __align__(16) char smem[131072];
    char* smemA = smem;            // +((cur*2)+kh)*16384
    char* smemB = smem + 65536;
    const int tid  = threadIdx.x;
    const int wave = tid >> 6, lane = tid & 63;
    const int quad = lane >> 4, l16 = lane & 15;
    const int wm = wave >> 2, wn = wave & 3;  // wave -> (M-half, N-quarter)
    // XCD-contiguous swizzle: 256 blocks round-robin 8 XCDs; each XCD gets a
    // contiguous 4Mx8N panel set (A k-slice then L2-shared by its 8 n-blocks).
    const int wg = ((int)blockIdx.x & 7) * 32 + ((int)blockIdx.x >> 3);
    const int m0 = (wg >> 3) * 256;
    const int n0 = (wg & 7) * 256;

    // fragment read offset in a [256][64B] arena (macro-row form); verified
    // conflict-free per 8-lane group (banks {0,4,1,5,2,6,3,7}).
    const int laneOff = (l16 >> 1) * 128 + (((((l16 & 1) << 2) | quad)) ^ (l16 >> 1)) * 16;

    // stage one (matrix, khalf) = 256 rows x 32 cols: 2 loads/thread
    auto stage2 = [&](const __hip_bfloat16* G, char* arena, int row0, int col0) {
#pragma unroll
        for (int i = 0; i < 2; ++i) {
            int s  = i * 512 + wave * 64 + lane;      // phys 16B slot
            int mm = i * 64 + wave * 8 + (lane >> 3); // macro-row; mm&7 == lane>>3
            int cc = (lane & 7) ^ (lane >> 3);        // logical chunk in macro-row
            int r  = 2 * mm + (cc >> 2);
            int c  = cc & 3;
            async_copy16(G + (size_t)(row0 + r) * K + col0 + c * 8, arena + s * 16);
        }
    };

    floatx4 acc[8][4];
#pragma unroll
    for (int i = 0; i < 8; ++i)
#pragma unroll
        for (int j = 0; j < 4; ++j) acc[i][j] = (floatx4)0.0f;

    const int nt = K / 64;  // 32 K-tiles

    // prologue: issue tile 0's four half-stages (8 loads); first loop iteration
    // waits them via vmcnt(8) after issuing tile 1's 8.
    stage2(Ab, smemA + 0,     m0, 0);
    stage2(Bb, smemB + 0,     n0, 0);
    stage2(Ab, smemA + 16384, m0, 32);
    stage2(Bb, smemB + 16384, n0, 32);

    for (int kt = 0; kt < nt; ++kt) {
        const int cur = kt & 1;
        __builtin_amdgcn_s_barrier();       // all waves done reading buf[cur^1]
        __builtin_amdgcn_sched_barrier(0);  // pin stage issues below the barrier
        if (kt + 1 < nt) {
            const int colb = (kt + 1) * 64;
            stage2(Ab, smemA + ((cur ^ 1) * 2 + 0) * 16384, m0, colb);
            stage2(Bb, smemB + ((cur ^ 1) * 2 + 0) * 16384, n0, colb);
            stage2(Ab, smemA + ((cur ^ 1) * 2 + 1) * 16384, m0, colb + 32);
            stage2(Bb, smemB + ((cur ^ 1) * 2 + 1) * 16384, n0, colb + 32);
            asm volatile("s_waitcnt vmcnt(8)" ::: "memory");  // tile kt landed
        } else {
            asm volatile("s_waitcnt vmcnt(0)" ::: "memory");  // last tile: drain
        }
        __builtin_amdgcn_sched_barrier(0);  // pin ds_reads below the wait

#pragma unroll
        for (int kh = 0; kh < 2; ++kh) {
            const char* Ab_ = smemA + (cur * 2 + kh) * 16384 + wm * 8192;
            const char* Bb_ = smemB + (cur * 2 + kh) * 16384 + wn * 4096;
            short8 bf[4], af[8];
#pragma unroll
            for (int n = 0; n < 4; ++n)
                bf[n] = *(const short8*)(Bb_ + n * 1024 + laneOff);
#pragma unroll
            for (int i = 0; i < 8; ++i)
                af[i] = *(const short8*)(Ab_ + i * 1024 + laneOff);
            __builtin_amdgcn_s_setprio(1);
#pragma unroll
            for (int i = 0; i < 8; ++i)
#pragma unroll
                for (int n = 0; n < 4; ++n)
                    acc[i][n] = __builtin_amdgcn_mfma_f32_16x16x32_bf16(
                        af[i], bf[n], acc[i][n], 0, 0, 0);
            __builtin_amdgcn_s_setprio(0);
        }
    }

    // epilogue: per wave 128x64 block of C
#pragma unroll
    for (int mf = 0; mf < 8; ++mf) {
#pragma unroll
        for (int nf = 0; nf < 4; ++nf) {
            int col  = n0 + wn * 64 + nf * 16 + l16;
            float bv = bias[col];
#pragma unroll
            for (int r = 0; r < 4; ++r) {
                int row = m0 + wm * 128 + mf * 16 + quad * 4 + r;
                float v = acc[mf][nf][r] + bv;
                if (STORE_MODE == 0) {
                    ((float*)Cv)[(size_t)row * N + col] = v;
                } else {
                    ((__hip_bfloat16*)Cv)[(size_t)row * N + col] = __float2bfloat16(v);
                }
            }
        }
    }
}

// ---------------------------------------------------------------- GEMM (legacy 128x128)
// kept for the tight-workspace path (f32 inputs, sync cvt).
template <int A_ASYNC, int B_ASYNC, int STORE_MODE>
__global__ __launch_bounds__(256, 2) void gemm_k(const void* __restrict__ Av,
                                                 const void* __restrict__ Bv,
                                                 const float* __restrict__ bias,
                                                 void* __restrict__ Cv,
                                                 int M, int N, int K) {
    __shared__ __align__(16) __hip_bfloat16 sA[128 * 32];
    __shared__ __align__(16) __hip_bfloat16 sB[128 * 32];
    const int tid  = threadIdx.x;
    const int wave = tid >> 6, lane = tid & 63;
    const int quad = lane >> 4, l16 = lane & 15;
    const int m0 = blockIdx.x * 128, n0 = blockIdx.y * 128;
    const int wm = (wave >> 1) * 64, wn = (wave & 1) * 64;
    const int lrow   = lane >> 2;
    const int srcoff = (((lane & 3) ^ ((lane >> 3) & 3)) * 16);
    const int dstoff = (lane & 3) * 16;
    const int swzq   = (quad ^ ((l16 >> 1) & 3)) * 16;

    floatx4 acc[4][4];
#pragma unroll
    for (int i = 0; i < 4; i++)
#pragma unroll
        for (int j = 0; j < 4; j++) acc[i][j] = (floatx4)0.0f;

    for (int k0 = 0; k0 < K; k0 += 32) {
        short8 va[2], vb[2];
#pragma unroll
        for (int c = 0; c < 2; ++c) {
            int r = wave * 32 + c * 16 + lrow;
            if (!A_ASYNC) va[c] = cvt8((const float*)Av + (size_t)(m0 + r) * K + k0 + (lane & 3) * 8);
            if (!B_ASYNC) vb[c] = cvt8((const float*)Bv + (size_t)(n0 + r) * K + k0 + (lane & 3) * 8);
        }
        __syncthreads();
#pragma unroll
        for (int c = 0; c < 2; ++c) {
            int r = wave * 32 + c * 16 + lrow;
            if (A_ASYNC)
                async_copy16((const char*)((const __hip_bfloat16*)Av + (size_t)(m0 + r) * K + k0) + srcoff,
                             (char*)sA + r * 64 + dstoff);
            else
                *(short8*)((char*)sA + r * 64 + srcoff) = va[c];
            if (B_ASYNC)
                async_copy16((const char*)((const __hip_bfloat16*)Bv + (size_t)(n0 + r) * K + k0) + srcoff,
                             (char*)sB + r * 64 + dstoff);
            else
                *(short8*)((char*)sB + r * 64 + srcoff) = vb[c];
        }
        __syncthreads();

        short8 af[4], bf[4];
#pragma unroll
        for (int i = 0; i < 4; i++)
            af[i] = *(const short8*)((const char*)sA + (wm + i * 16 + l16) * 64 + swzq);
#pragma unroll
        for (int j = 0; j < 4; j++)
            bf[j] = *(const short8*)((const char*)sB + (wn + j * 16 + l16) * 64 + swzq);
#pragma unroll
        for (int i = 0; i < 4; i++)
#pragma unroll
            for (int j = 0; j < 4; j++)
                acc[i][j] = __builtin_amdgcn_mfma_f32_16x16x32_bf16(af[i], bf[j], acc[i][j], 0, 0, 0);
    }

#pragma unroll
    for (int i = 0; i < 4; i++) {
#pragma unroll
        for (int j = 0; j < 4; j++) {
            int col  = n0 + wn + j * 16 + l16;
            float bv = bias[col];
#pragma unroll
            for (int r = 0; r < 4; ++r) {
                int row = m0 + wm + i * 16 + quad * 4 + r;
                float v = acc[i][j][r] + bv;
                if (STORE_MODE == 0) {
                    ((float*)Cv)[(size_t)row * N + col] = v;
                } else if (STORE_MODE == 1) {
                    ((__hip_bfloat16*)Cv)[(size_t)row * N + col] = __float2bfloat16(v);
                } else {
                    int s = row >> 2, b = row & 3, nh = col >> 7, d = col & 127;
                    ((__hip_bfloat16*)Cv)[((size_t)(b * 16 + nh) * 128 + d) * 2048 + s] =
                        __float2bfloat16(v);
                }
            }
        }
    }
}

// ---------------------------------------------------------------- RoPE (in-place)
__global__ __launch_bounds__(256) void rope_kernel(__hip_bfloat16* __restrict__ Q,
                                                   __hip_bfloat16* __restrict__ K) {
    const int PER = 8192 * 16 * 32;
    int idx = (int)blockIdx.x * 256 + (int)threadIdx.x;
    __hip_bfloat16* base = (idx < PER) ? Q : K;
    int i  = (idx < PER) ? idx : idx - PER;
    int p  = i & 31;
    int nh = (i >> 5) & 15;
    int t  = i >> 9;
    int s  = t >> 2;
    float inv = __expf(-(float)(p & 15) * 0.5756462732485115f);  // ln(10000)/16
    float ang = (float)s * inv;
    float c = cosf(ang), sn = sinf(ang);
    size_t off = (size_t)t * 2048 + nh * 128 + 2 * p;
    float x0 = __bfloat162float(base[off]);
    float x1 = __bfloat162float(base[off + 1]);
    base[off]     = __float2bfloat16(x0 * c - x1 * sn);
    base[off + 1] = __float2bfloat16(x0 * sn + x1 * c);
}

// ---------------------------------------------------------------- flash attention
// (unchanged from round 4: swapped-operand in-register softmax + T3/T4 counted
//  vmcnt double-buffer; verified 123us, MfmaUtil 25%)
__global__ __launch_bounds__(256, 2) void attn_kernel(__hip_bfloat16* __restrict__ Qio,
                                                      const __hip_bfloat16* __restrict__ Km,
                                                      const __hip_bfloat16* __restrict__ Vt) {
    __shared__ __align__(16) char smem[65536];
    const int tid  = threadIdx.x;
    const int wave = tid >> 6, lane = tid & 63;
    const int quad = lane >> 4, l16 = lane & 15;
    const int bh = blockIdx.x, b = bh >> 4, nh = bh & 15;
    const int qtl = 15 - (int)blockIdx.y;
    const int q0  = qtl * 128;
    const int lrow    = lane >> 2;
    const int dstoff  = (lane & 3) * 16;
    const int srcoffV = (((lane & 3) ^ ((lane >> 3) & 3)) * 16);
    const int swzqV   = (quad ^ ((l16 >> 1) & 3)) * 16;
    const float scale = 0.08838834764831845f;

    auto stage = [&](int kt, int p) {
        char* sKb = smem + p * 32768;
        char* sVb = sKb + 16384;
#pragma unroll
        for (int c = 0; c < 4; ++c) {
            int krow = c * 16 + lrow;
            int swzK = ((krow >> 1) & 1) | (((krow >> 3) & 1) << 1);
            int srcK = ((lane & 3) ^ swzK) * 16;
            int t    = (kt * 64 + krow) * 4 + b;
            async_copy16((const char*)(Km + (size_t)t * 2048 + nh * 128 + wave * 32) + srcK,
                         sKb + wave * 4096 + krow * 64 + dstoff);
        }
        const int kc = wave >> 1, dh = (wave & 1) * 64;
#pragma unroll
        for (int c = 0; c < 4; ++c) {
            int d = dh + c * 16 + lrow;
            async_copy16((const char*)(Vt + ((size_t)bh * 128 + d) * 2048 + kt * 64 + kc * 32) + srcoffV,
                         sVb + kc * 8192 + d * 64 + dstoff);
        }
    };

    short8 qf[2][4];
#pragma unroll
    for (int mg = 0; mg < 2; ++mg)
#pragma unroll
        for (int kk = 0; kk < 4; ++kk) {
            int qrow = wave * 32 + mg * 16 + l16;
            int t    = (q0 + qrow) * 4 + b;
            qf[mg][kk] = *(const short8*)(Qio + (size_t)t * 2048 + nh * 128 + kk * 32 + quad * 8);
        }

    float m_i[2], l_i[2];
#pragma unroll
    for (int mg = 0; mg < 2; ++mg) { m_i[mg] = -1e30f; l_i[mg] = 0.f; }
    floatx4 o_acc[2][8];
#pragma unroll
    for (int mg = 0; mg < 2; ++mg)
#pragma unroll
        for (int n = 0; n < 8; ++n) o_acc[mg][n] = (floatx4)0.0f;

    const int nk = 2 * qtl + 2;

    stage(0, 0);
    __syncthreads();

    for (int kt = 0; kt < nk; ++kt) {
        const int cur = kt & 1;
        if (kt + 1 < nk) {
            stage(kt + 1, cur ^ 1);
            asm volatile("s_waitcnt vmcnt(8)" ::: "memory");
        } else {
            asm volatile("s_waitcnt vmcnt(0)" ::: "memory");
        }
        __builtin_amdgcn_s_barrier();
        __builtin_amdgcn_sched_barrier(0);

        const char* sKb = smem + cur * 32768;
        const char* sVb = sKb + 16384;

        floatx4 sacc[2][4];
#pragma unroll
        for (int mg = 0; mg < 2; ++mg)
#pragma unroll
            for (int n = 0; n < 4; ++n) sacc[mg][n] = (floatx4)0.0f;
#pragma unroll
        for (int nt = 0; nt < 4; ++nt) {
            int R    = (nt >> 1) * 32 + (l16 >> 2) * 8 + (nt & 1) * 4 + (l16 & 3);
            int swzK = ((R >> 1) & 1) | (((R >> 3) & 1) << 1);
            int off  = R * 64 + (quad ^ swzK) * 16;
#pragma unroll
            for (int kk = 0; kk < 4; ++kk) {
                short8 ak = *(const short8*)(sKb + kk * 4096 + off);
                sacc[0][nt] = __builtin_amdgcn_mfma_f32_16x16x32_bf16(ak, qf[0][kk], sacc[0][nt], 0, 0, 0);
                sacc[1][nt] = __builtin_amdgcn_mfma_f32_16x16x32_bf16(ak, qf[1][kk], sacc[1][nt], 0, 0, 0);
            }
        }

        short8 ap[2][2];
#pragma unroll
        for (int mg = 0; mg < 2; ++mg) {
            const int q     = q0 + wave * 32 + mg * 16 + l16;
            const bool dmask = (kt * 64 + 63) > (q0 + wave * 32 + mg * 16);
            float mx = -1e30f;
#pragma unroll
            for (int nt = 0; nt < 4; ++nt) {
                int kvb = kt * 64 + (nt >> 1) * 32 + quad * 8 + (nt & 1) * 4;
#pragma unroll
                for (int r = 0; r < 4; ++r) {
                    float v = sacc[mg][nt][r] * scale;
                    if (dmask && (kvb + r > q)) v = -1e30f;
                    sacc[mg][nt][r] = v;
                    mx = fmaxf(mx, v);
                }
            }
            mx = fmaxf(mx, __shfl_xor(mx, 16, 64));
            mx = fmaxf(mx, __shfl_xor(mx, 32, 64));
            float mnew  = fmaxf(m_i[mg], mx);
            float alpha = __expf(m_i[mg] - mnew);
            m_i[mg] = mnew;
            float rs = 0.f;
#pragma unroll
            for (int nt = 0; nt < 4; ++nt)
#pragma unroll
                for (int r = 0; r < 4; ++r) {
                    float e = __expf(sacc[mg][nt][r] - mnew);
                    sacc[mg][nt][r] = e;
                    rs += e;
                }
            rs += __shfl_xor(rs, 16, 64);
            rs += __shfl_xor(rs, 32, 64);
            l_i[mg] = l_i[mg] * alpha + rs;
#pragma unroll
            for (int kc = 0; kc < 2; ++kc) {
                union { short s[8]; short8 v; } u;
                __hip_bfloat16* h = (__hip_bfloat16*)u.s;
                h[0] = __float2bfloat16(sacc[mg][2 * kc][0]);
                h[1] = __float2bfloat16(sacc[mg][2 * kc][1]);
                h[2] = __float2bfloat16(sacc[mg][2 * kc][2]);
                h[3] = __float2bfloat16(sacc[mg][2 * kc][3]);
                h[4] = __float2bfloat16(sacc[mg][2 * kc + 1][0]);
                h[5] = __float2bfloat16(sacc[mg][2 * kc + 1][1]);
                h[6] = __float2bfloat16(sacc[mg][2 * kc + 1][2]);
                h[7] = __float2bfloat16(sacc[mg][2 * kc + 1][3]);
                ap[mg][kc] = u.v;
            }
#pragma unroll
            for (int nt = 0; nt < 8; ++nt)
#pragma unroll
                for (int r = 0; r < 4; ++r) o_acc[mg][nt][r] *= alpha;
        }

#pragma unroll
        for (int kc = 0; kc < 2; ++kc)
#pragma unroll
            for (int nt = 0; nt < 8; ++nt) {
                short8 av = *(const short8*)(sVb + kc * 8192 + (nt * 16 + l16) * 64 + swzqV);
                o_acc[0][nt] = __builtin_amdgcn_mfma_f32_16x16x32_bf16(av, ap[0][kc], o_acc[0][nt], 0, 0, 0);
                o_acc[1][nt] = __builtin_amdgcn_mfma_f32_16x16x32_bf16(av, ap[1][kc], o_acc[1][nt], 0, 0, 0);
            }

        asm volatile("s_waitcnt lgkmcnt(0)" ::: "memory");
        __builtin_amdgcn_s_barrier();
        __builtin_amdgcn_sched_barrier(0);
    }

    char* sO = smem + wave * 4096;
#pragma unroll
    for (int mg = 0; mg < 2; ++mg) {
        float inv = 1.0f / l_i[mg];
#pragma unroll
        for (int nt = 0; nt < 8; ++nt) {
            union { short h[4]; uint2 v; } u;
            __hip_bfloat16* hh = (__hip_bfloat16*)u.h;
            hh[0] = __float2bfloat16(o_acc[mg][nt][0] * inv);
            hh[1] = __float2bfloat16(o_acc[mg][nt][1] * inv);
            hh[2] = __float2bfloat16(o_acc[mg][nt][2] * inv);
            hh[3] = __float2bfloat16(o_acc[mg][nt][3] * inv);
            int pc = (2 * nt + (quad >> 1)) ^ ((l16 >> 1) & 3);
            *(uint2*)(sO + l16 * 256 + pc * 16 + (quad & 1) * 8) = u.v;
        }
#pragma unroll
        for (int cc = 0; cc < 4; ++cc) {
            int qr  = lane >> 2;
            int c16 = (lane & 3) + cc * 4;
            int pc  = c16 ^ ((qr >> 1) & 3);
            short8 ov = *(const short8*)(sO + qr * 256 + pc * 16);
            int s = q0 + wave * 32 + mg * 16 + qr;
            *(short8*)(Qio + (size_t)(s * 4 + b) * 2048 + nh * 128 + c16 * 8) = ov;
        }
    }
}

// ---------------------------------------------------------------- launch
extern "C" void kernel_launch(void* const* d_in, const int* in_sizes, int n_in,
                              void* d_out, int out_size, void* d_ws, size_t ws_size,
                              hipStream_t stream) {
    const float* x  = (const float*)d_in[0];
    const float* wq = (const float*)d_in[1];
    const float* bq = (const float*)d_in[2];
    const float* wk = (const float*)d_in[3];
    const float* bk = (const float*)d_in[4];
    const float* wv = (const float*)d_in[5];
    const float* bv = (const float*)d_in[6];
    const float* wd = (const float*)d_in[7];
    const float* bd = (const float*)d_in[8];
    // d_in[9] = start_pos: unused (reference recomputes t=arange(seq))

    const size_t TH = (size_t)8192 * 2048;  // 16.7M elems
    const size_t HH = (size_t)2048 * 2048;  // 4M elems

    if (ws_size >= (136ull << 20)) {
        // spacious: pre-convert to bf16; 256x256 gemms; V normal layout goes to
        // d_out as scratch (freed by vtrans before the final projection).
        __hip_bfloat16* xb  = (__hip_bfloat16*)d_ws;
        __hip_bfloat16* Qb  = xb + TH;
        __hip_bfloat16* Kb  = Qb + TH;
        __hip_bfloat16* Vtb = Kb + TH;
        __hip_bfloat16* wb  = Vtb + TH;  // reused per GEMM
        __hip_bfloat16* Vn  = (__hip_bfloat16*)d_out;  // scratch: V normal layout

        cvt_bf16<<<(int)(TH / 1024), 256, 0, stream>>>(x, xb, (int)TH);
        cvt_bf16<<<(int)(HH / 1024), 256, 0, stream>>>(wq, wb, (int)HH);
        gemm256<1><<<256, 512, 0, stream>>>(xb, wb, bq, Qb);
        cvt_bf16<<<(int)(HH / 1024), 256, 0, stream>>>(wk, wb, (int)HH);
        gemm256<1><<<256, 512, 0, stream>>>(xb, wb, bk, Kb);
        cvt_bf16<<<(int)(HH / 1024), 256, 0, stream>>>(wv, wb, (int)HH);
        gemm256<1><<<256, 512, 0, stream>>>(xb, wb, bv, Vn);
        vtrans<<<8192, 256, 0, stream>>>(Vn, Vtb);

        rope_kernel<<<32768, 256, 0, stream>>>(Qb, Kb);
        attn_kernel<<<dim3(64, 16), 256, 0, stream>>>(Qb, Kb, Vtb);

        cvt_bf16<<<(int)(HH / 1024), 256, 0, stream>>>(wd, wb, (int)HH);
        gemm256<0><<<256, 512, 0, stream>>>(Qb, wb, bd, d_out);
    } else {
        // tight (96 MiB total scratch): Q in ws; K,Vt inside d_out (legacy path)
        __hip_bfloat16* Qb = (__hip_bfloat16*)d_ws;
        __hip_bfloat16* Kb = (__hip_bfloat16*)d_out;
        __hip_bfloat16* Vt = (__hip_bfloat16*)d_out + TH;
        dim3 gg(64, 16);

        gemm_k<0, 0, 1><<<gg, 256, 0, stream>>>(x, wq, bq, Qb, 8192, 2048, 2048);
        gemm_k<0, 0, 1><<<gg, 256, 0, stream>>>(x, wk, bk, Kb, 8192, 2048, 2048);
        gemm_k<0, 0, 2><<<gg, 256, 0, stream>>>(x, wv, bv, Vt, 8192, 2048, 2048);

        rope_kernel<<<32768, 256, 0, stream>>>(Qb, Kb);
        attn_kernel<<<dim3(64, 16), 256, 0, stream>>>(Qb, Kb, Vt);

        gemm_k<1, 0, 0><<<gg, 256, 0, stream>>>(Qb, wd, bd, d_out, 8192, 2048, 2048);
    }
    (void)in_sizes; (void)n_in; (void)out_size; (void)ws_size;
}